// Round 1
// baseline (449.928 us; speedup 1.0000x reference)
//
#include <hip/hip_runtime.h>
#include <math.h>

#define NN   20000
#define INF  256
#define HID  256   // H*OUT = 4*64
#define NH   4
#define OUTF 64

__device__ __forceinline__ float lrelu(float x){ return x > 0.f ? x : 0.2f*x; }
__device__ __forceinline__ float elu(float x){ return x > 0.f ? x : __expf(x)-1.f; }

// ---------------- CSR build ----------------
__global__ void k_deg_init(int* deg){
    int i = blockIdx.x*blockDim.x + threadIdx.x;
    if (i < NN) deg[i] = 1;               // self-loop
}

__global__ void k_deg_hist(const int* __restrict__ ei, int* deg, int E){
    int e = blockIdx.x*blockDim.x + threadIdx.x;
    if (e < E) atomicAdd(&deg[ei[E + e]], 1);   // dst = ei[1][e]
}

__global__ void k_scan(const int* __restrict__ deg, int* __restrict__ rowptr){
    __shared__ int part[1024];
    int t = threadIdx.x;
    const int CH = 20;                    // 1024*20 >= 20000
    int base = t*CH;
    int s = 0;
    for (int i = 0; i < CH; i++){ int idx = base+i; if (idx < NN) s += deg[idx]; }
    part[t] = s;
    __syncthreads();
    for (int off = 1; off < 1024; off <<= 1){
        int v = (t >= off) ? part[t-off] : 0;
        __syncthreads();
        part[t] += v;
        __syncthreads();
    }
    int run = (t > 0) ? part[t-1] : 0;
    for (int i = 0; i < CH; i++){
        int idx = base+i;
        if (idx < NN){ rowptr[idx] = run; run += deg[idx]; }
    }
    if (t == 1023) rowptr[NN] = part[1023];
}

__global__ void k_selfloop(const int* __restrict__ rowptr, int* col, int* cursor){
    int n = blockIdx.x*blockDim.x + threadIdx.x;
    if (n < NN){ int p = rowptr[n]; col[p] = n; cursor[n] = p+1; }
}

__global__ void k_scatter(const int* __restrict__ ei, int* cursor, int* col, int E){
    int e = blockIdx.x*blockDim.x + threadIdx.x;
    if (e < E){
        int s = ei[e], d = ei[E + e];
        int pos = atomicAdd(&cursor[d], 1);
        col[pos] = s;
    }
}

// ---------------- Layer 1 GEMM: h1 = x @ W1  [20000,256]x[256,256] ----------------
__global__ void k_gemm1(const float* __restrict__ x, const float* __restrict__ W,
                        float* __restrict__ h1){
    __shared__ float xs[16][INF];
    int row0 = blockIdx.x*16;
    int t = threadIdx.x;
    for (int i = t; i < 16*INF; i += 256)
        xs[i>>8][i&255] = x[(size_t)(row0 + (i>>8))*INF + (i&255)];
    __syncthreads();
    float acc[16];
    #pragma unroll
    for (int r = 0; r < 16; r++) acc[r] = 0.f;
    for (int k = 0; k < INF; k++){
        float w = W[k*HID + t];
        #pragma unroll
        for (int r = 0; r < 16; r++) acc[r] = fmaf(xs[r][k], w, acc[r]);
    }
    #pragma unroll
    for (int r = 0; r < 16; r++) h1[(size_t)(row0+r)*HID + t] = acc[r];
}

// ---------------- attention coefficients, layer 1 ----------------
__global__ void k_coef1(const float* __restrict__ h1, const float* __restrict__ att_s,
                        const float* __restrict__ att_d, float* __restrict__ as1,
                        float* __restrict__ ad1){
    int wv = threadIdx.x >> 6, lane = threadIdx.x & 63;
    int n = blockIdx.x*4 + wv;
    if (n >= NN) return;
    float4 v  = ((const float4*)(h1 + (size_t)n*HID))[lane];   // elements 4l..4l+3
    float4 s4 = ((const float4*)att_s)[lane];
    float4 d4 = ((const float4*)att_d)[lane];
    float ps = v.x*s4.x + v.y*s4.y + v.z*s4.z + v.w*s4.w;
    float pd = v.x*d4.x + v.y*d4.y + v.z*d4.z + v.w*d4.w;
    // head = lane>>4 ; reduce within each 16-lane group
    #pragma unroll
    for (int off = 1; off < 16; off <<= 1){
        ps += __shfl_xor(ps, off, 64);
        pd += __shfl_xor(pd, off, 64);
    }
    if ((lane & 15) == 0){
        int h = lane >> 4;
        as1[n*NH + h] = ps;
        ad1[n*NH + h] = pd;
    }
}

// ---------------- layer-1 softmax + aggregate + bias + ELU -> x1 ----------------
__global__ void k_agg1(const float* __restrict__ h1, const int* __restrict__ rowptr,
                       const int* __restrict__ col, const float* __restrict__ as1,
                       const float* __restrict__ ad1, const float* __restrict__ bias,
                       float* __restrict__ x1){
    int wv = threadIdx.x >> 6, lane = threadIdx.x & 63;
    int n = blockIdx.x*4 + wv;
    if (n >= NN) return;
    int beg = rowptr[n], end = rowptr[n+1];
    float4 adst = ((const float4*)ad1)[n];

    // pass 1: per-head max (lane-parallel over edges)
    float m0=-1e30f, m1=-1e30f, m2=-1e30f, m3=-1e30f;
    for (int i = beg+lane; i < end; i += 64){
        float4 a = ((const float4*)as1)[col[i]];
        m0 = fmaxf(m0, lrelu(a.x+adst.x));
        m1 = fmaxf(m1, lrelu(a.y+adst.y));
        m2 = fmaxf(m2, lrelu(a.z+adst.z));
        m3 = fmaxf(m3, lrelu(a.w+adst.w));
    }
    #pragma unroll
    for (int off = 32; off >= 1; off >>= 1){
        m0 = fmaxf(m0, __shfl_xor(m0, off, 64));
        m1 = fmaxf(m1, __shfl_xor(m1, off, 64));
        m2 = fmaxf(m2, __shfl_xor(m2, off, 64));
        m3 = fmaxf(m3, __shfl_xor(m3, off, 64));
    }
    // pass 2: per-head sum of exp
    float s0=0.f, s1=0.f, s2=0.f, s3=0.f;
    for (int i = beg+lane; i < end; i += 64){
        float4 a = ((const float4*)as1)[col[i]];
        s0 += __expf(lrelu(a.x+adst.x)-m0);
        s1 += __expf(lrelu(a.y+adst.y)-m1);
        s2 += __expf(lrelu(a.z+adst.z)-m2);
        s3 += __expf(lrelu(a.w+adst.w)-m3);
    }
    #pragma unroll
    for (int off = 32; off >= 1; off >>= 1){
        s0 += __shfl_xor(s0, off, 64);
        s1 += __shfl_xor(s1, off, 64);
        s2 += __shfl_xor(s2, off, 64);
        s3 += __shfl_xor(s3, off, 64);
    }
    // pass 3: aggregate (whole wave per edge); lane owns elements 4l..4l+3, head = lane>>4
    int h = lane >> 4;
    float mh  = h==0?m0 : h==1?m1 : h==2?m2 : m3;
    float sh  = h==0?s0 : h==1?s1 : h==2?s2 : s3;
    float adh = h==0?adst.x : h==1?adst.y : h==2?adst.z : adst.w;
    float rs = 1.f/(sh + 1e-16f);
    float ax=0.f, ay=0.f, az=0.f, aw=0.f;
    for (int i = beg; i < end; i++){
        int s = col[i];
        float4 a = ((const float4*)as1)[s];
        float ash = h==0?a.x : h==1?a.y : h==2?a.z : a.w;
        float alpha = __expf(lrelu(ash+adh)-mh) * rs;
        float4 hv = ((const float4*)(h1 + (size_t)s*HID))[lane];
        ax = fmaf(alpha, hv.x, ax);
        ay = fmaf(alpha, hv.y, ay);
        az = fmaf(alpha, hv.z, az);
        aw = fmaf(alpha, hv.w, aw);
    }
    float4 b = ((const float4*)bias)[lane];
    float4 o;
    o.x = elu(ax + b.x);
    o.y = elu(ay + b.y);
    o.z = elu(az + b.z);
    o.w = elu(aw + b.w);
    ((float4*)(x1 + (size_t)n*HID))[lane] = o;
}

// ---------------- Layer 2 GEMM: h2 = x1 @ W2  [20000,256]x[256,64] ----------------
__global__ void k_gemm2(const float* __restrict__ x1, const float* __restrict__ W2,
                        float* __restrict__ h2){
    __shared__ float xs[32][HID];         // 32 KB
    int row0 = blockIdx.x*32;
    int t = threadIdx.x;
    for (int i = t; i < 32*HID; i += 256)
        xs[i>>8][i&255] = x1[(size_t)(row0 + (i>>8))*HID + (i&255)];
    __syncthreads();
    int c  = t & 63;
    int r0 = (t >> 6)*8;
    float acc[8];
    #pragma unroll
    for (int r = 0; r < 8; r++) acc[r] = 0.f;
    for (int k = 0; k < HID; k++){
        float w = W2[k*OUTF + c];
        #pragma unroll
        for (int r = 0; r < 8; r++) acc[r] = fmaf(xs[r0+r][k], w, acc[r]);
    }
    #pragma unroll
    for (int r = 0; r < 8; r++) h2[(size_t)(row0+r0+r)*OUTF + c] = acc[r];
}

// ---------------- attention coefficients, layer 2 ----------------
__global__ void k_coef2(const float* __restrict__ h2, const float* __restrict__ att_s,
                        const float* __restrict__ att_d, float* __restrict__ a2s,
                        float* __restrict__ a2d){
    int wv = threadIdx.x >> 6, lane = threadIdx.x & 63;
    int n = blockIdx.x*4 + wv;
    if (n >= NN) return;
    float v = h2[(size_t)n*OUTF + lane];
    float ps = v*att_s[lane], pd = v*att_d[lane];
    #pragma unroll
    for (int off = 32; off >= 1; off >>= 1){
        ps += __shfl_xor(ps, off, 64);
        pd += __shfl_xor(pd, off, 64);
    }
    if (lane == 0){ a2s[n] = ps; a2d[n] = pd; }
}

// ---------------- layer-2 softmax + aggregate + bias -> out ----------------
__global__ void k_agg2(const float* __restrict__ h2, const int* __restrict__ rowptr,
                       const int* __restrict__ col, const float* __restrict__ a2s,
                       const float* __restrict__ a2d, const float* __restrict__ bias2,
                       float* __restrict__ out){
    int wv = threadIdx.x >> 6, lane = threadIdx.x & 63;
    int n = blockIdx.x*4 + wv;
    if (n >= NN) return;
    int beg = rowptr[n], end = rowptr[n+1];
    float adh = a2d[n];
    float m = -1e30f;
    for (int i = beg+lane; i < end; i += 64) m = fmaxf(m, lrelu(a2s[col[i]]+adh));
    #pragma unroll
    for (int off = 32; off >= 1; off >>= 1) m = fmaxf(m, __shfl_xor(m, off, 64));
    float sden = 0.f;
    for (int i = beg+lane; i < end; i += 64) sden += __expf(lrelu(a2s[col[i]]+adh)-m);
    #pragma unroll
    for (int off = 32; off >= 1; off >>= 1) sden += __shfl_xor(sden, off, 64);
    float rs = 1.f/(sden + 1e-16f);
    float acc = 0.f;
    for (int i = beg; i < end; i++){
        int s = col[i];
        float alpha = __expf(lrelu(a2s[s]+adh)-m) * rs;
        acc = fmaf(alpha, h2[(size_t)s*OUTF + lane], acc);
    }
    out[(size_t)n*OUTF + lane] = acc + bias2[lane];
}

extern "C" void kernel_launch(void* const* d_in, const int* in_sizes, int n_in,
                              void* d_out, int out_size, void* d_ws, size_t ws_size,
                              hipStream_t stream){
    const float* x      = (const float*)d_in[0];
    const int*   ei     = (const int*)  d_in[1];
    const float* W1     = (const float*)d_in[2];
    const float* att_s1 = (const float*)d_in[3];
    const float* att_d1 = (const float*)d_in[4];
    const float* bias1  = (const float*)d_in[5];
    const float* W2     = (const float*)d_in[6];
    const float* att_s2 = (const float*)d_in[7];
    const float* att_d2 = (const float*)d_in[8];
    const float* bias2  = (const float*)d_in[9];
    int E = in_sizes[1] / 2;

    char* w = (char*)d_ws;
    size_t off = 0;
    auto alloc = [&](size_t b){ void* p = w + off; off += (b + 255) & ~(size_t)255; return p; };
    float* h1     = (float*)alloc((size_t)NN*HID*4);
    float* x1     = (float*)alloc((size_t)NN*HID*4);
    float* h2     = (float*)alloc((size_t)NN*OUTF*4);
    float* as1    = (float*)alloc((size_t)NN*NH*4);
    float* ad1    = (float*)alloc((size_t)NN*NH*4);
    float* a2s    = (float*)alloc((size_t)NN*4);
    float* a2d    = (float*)alloc((size_t)NN*4);
    int*   deg    = (int*)alloc((size_t)(NN+1)*4);
    int*   rowptr = (int*)alloc((size_t)(NN+1)*4);
    int*   cursor = (int*)alloc((size_t)NN*4);
    int*   col    = (int*)alloc((size_t)(E+NN)*4);

    k_deg_init<<<(NN+255)/256, 256, 0, stream>>>(deg);
    k_deg_hist<<<(E+255)/256, 256, 0, stream>>>(ei, deg, E);
    k_scan<<<1, 1024, 0, stream>>>(deg, rowptr);
    k_selfloop<<<(NN+255)/256, 256, 0, stream>>>(rowptr, col, cursor);
    k_scatter<<<(E+255)/256, 256, 0, stream>>>(ei, cursor, col, E);

    k_gemm1<<<NN/16, 256, 0, stream>>>(x, W1, h1);
    k_coef1<<<(NN+3)/4, 256, 0, stream>>>(h1, att_s1, att_d1, as1, ad1);
    k_agg1<<<(NN+3)/4, 256, 0, stream>>>(h1, rowptr, col, as1, ad1, bias1, x1);

    k_gemm2<<<NN/32, 256, 0, stream>>>(x1, W2, h2);
    k_coef2<<<(NN+3)/4, 256, 0, stream>>>(h2, att_s2, att_d2, a2s, a2d);
    k_agg2<<<(NN+3)/4, 256, 0, stream>>>(h2, rowptr, col, a2s, a2d, bias2, (float*)d_out);
}

// Round 2
// 377.930 us; speedup vs baseline: 1.1905x; 1.1905x over previous
//
#include <hip/hip_runtime.h>
#include <math.h>

#define NN   20000
#define INF  256
#define HID  256   // H*OUT = 4*64
#define NH   4
#define OUTF 64

__device__ __forceinline__ float lrelu(float x){ return x > 0.f ? x : 0.2f*x; }
__device__ __forceinline__ float elu(float x){ return x > 0.f ? x : __expf(x)-1.f; }

// ---------------- CSR build ----------------
__global__ void k_deg_init(int* deg){
    int i = blockIdx.x*blockDim.x + threadIdx.x;
    if (i < NN) deg[i] = 1;               // self-loop
}

__global__ void k_deg_hist(const int* __restrict__ ei, int* deg, int E){
    int e = blockIdx.x*blockDim.x + threadIdx.x;
    if (e < E) atomicAdd(&deg[ei[E + e]], 1);   // dst = ei[1][e]
}

__global__ void k_scan(const int* __restrict__ deg, int* __restrict__ rowptr){
    __shared__ int part[1024];
    int t = threadIdx.x;
    const int CH = 20;                    // 1024*20 >= 20000
    int base = t*CH;
    int s = 0;
    for (int i = 0; i < CH; i++){ int idx = base+i; if (idx < NN) s += deg[idx]; }
    part[t] = s;
    __syncthreads();
    for (int off = 1; off < 1024; off <<= 1){
        int v = (t >= off) ? part[t-off] : 0;
        __syncthreads();
        part[t] += v;
        __syncthreads();
    }
    int run = (t > 0) ? part[t-1] : 0;
    for (int i = 0; i < CH; i++){
        int idx = base+i;
        if (idx < NN){ rowptr[idx] = run; run += deg[idx]; }
    }
    if (t == 1023) rowptr[NN] = part[1023];
}

__global__ void k_selfloop(const int* __restrict__ rowptr, int* col, int* cursor){
    int n = blockIdx.x*blockDim.x + threadIdx.x;
    if (n < NN){ int p = rowptr[n]; col[p] = n; cursor[n] = p+1; }
}

__global__ void k_scatter(const int* __restrict__ ei, int* cursor, int* col, int E){
    int e = blockIdx.x*blockDim.x + threadIdx.x;
    if (e < E){
        int s = ei[e], d = ei[E + e];
        int pos = atomicAdd(&cursor[d], 1);
        col[pos] = s;
    }
}

// ---------- Layer 1 GEMM + fused attention coefficients ----------
// h1 = x @ W1 [20000,256]x[256,256]; wave wv covers cols of head wv.
__global__ void k_gemm1(const float* __restrict__ x, const float* __restrict__ W,
                        const float* __restrict__ att_s, const float* __restrict__ att_d,
                        float* __restrict__ h1, float* __restrict__ as1,
                        float* __restrict__ ad1){
    __shared__ float xs[16][INF];
    int row0 = blockIdx.x*16;
    int t = threadIdx.x;
    int lane = t & 63, wv = t >> 6;
    for (int i = t; i < 16*INF; i += 256)
        xs[i>>8][i&255] = x[(size_t)(row0 + (i>>8))*INF + (i&255)];
    __syncthreads();
    float acc[16];
    #pragma unroll
    for (int r = 0; r < 16; r++) acc[r] = 0.f;
    for (int k = 0; k < INF; k++){
        float w = W[k*HID + t];
        #pragma unroll
        for (int r = 0; r < 16; r++) acc[r] = fmaf(xs[r][k], w, acc[r]);
    }
    float sv = att_s[t], dv = att_d[t];     // col t -> head t>>6, att flat [256]
    #pragma unroll
    for (int r = 0; r < 16; r++){
        h1[(size_t)(row0+r)*HID + t] = acc[r];
        float ps = acc[r]*sv, pd = acc[r]*dv;
        #pragma unroll
        for (int off = 32; off >= 1; off >>= 1){
            ps += __shfl_xor(ps, off, 64);
            pd += __shfl_xor(pd, off, 64);
        }
        if (lane == 0){
            as1[(row0+r)*NH + wv] = ps;
            ad1[(row0+r)*NH + wv] = pd;
        }
    }
}

// ---------- layer-1 fused softmax+aggregate (single edge pass) ----------
__global__ void k_agg1(const float* __restrict__ h1, const int* __restrict__ rowptr,
                       const int* __restrict__ col, const float* __restrict__ as1,
                       const float* __restrict__ ad1, const float* __restrict__ bias,
                       float* __restrict__ x1){
    int wv = threadIdx.x >> 6, lane = threadIdx.x & 63;
    int n = blockIdx.x*4 + wv;
    if (n >= NN) return;
    int beg = rowptr[n], end = rowptr[n+1];
    float4 adst = ((const float4*)ad1)[n];
    int h = lane >> 4;
    float adh = h==0?adst.x : h==1?adst.y : h==2?adst.z : adst.w;
    float den = 0.f;
    float4 acc0 = {0,0,0,0}, acc1 = {0,0,0,0};

    for (int base = beg; base < end; base += 64){
        int cnt = min(64, end - base);
        int myidx = (lane < cnt) ? col[base + lane] : 0;
        int j = 0;
        for (; j + 4 <= cnt; j += 4){
            int s0 = __shfl(myidx, j,   64);
            int s1 = __shfl(myidx, j+1, 64);
            int s2 = __shfl(myidx, j+2, 64);
            int s3 = __shfl(myidx, j+3, 64);
            float4 hv0 = ((const float4*)(h1 + (size_t)s0*HID))[lane];
            float4 hv1 = ((const float4*)(h1 + (size_t)s1*HID))[lane];
            float4 hv2 = ((const float4*)(h1 + (size_t)s2*HID))[lane];
            float4 hv3 = ((const float4*)(h1 + (size_t)s3*HID))[lane];
            float4 a0 = ((const float4*)as1)[s0];
            float4 a1 = ((const float4*)as1)[s1];
            float4 a2 = ((const float4*)as1)[s2];
            float4 a3 = ((const float4*)as1)[s3];
            float e0 = h==0?a0.x : h==1?a0.y : h==2?a0.z : a0.w;
            float e1 = h==0?a1.x : h==1?a1.y : h==2?a1.z : a1.w;
            float e2 = h==0?a2.x : h==1?a2.y : h==2?a2.z : a2.w;
            float e3 = h==0?a3.x : h==1?a3.y : h==2?a3.z : a3.w;
            float w0 = __expf(lrelu(e0+adh));
            float w1 = __expf(lrelu(e1+adh));
            float w2 = __expf(lrelu(e2+adh));
            float w3 = __expf(lrelu(e3+adh));
            den += (w0 + w1) + (w2 + w3);
            acc0.x = fmaf(w0, hv0.x, acc0.x); acc0.y = fmaf(w0, hv0.y, acc0.y);
            acc0.z = fmaf(w0, hv0.z, acc0.z); acc0.w = fmaf(w0, hv0.w, acc0.w);
            acc1.x = fmaf(w1, hv1.x, acc1.x); acc1.y = fmaf(w1, hv1.y, acc1.y);
            acc1.z = fmaf(w1, hv1.z, acc1.z); acc1.w = fmaf(w1, hv1.w, acc1.w);
            acc0.x = fmaf(w2, hv2.x, acc0.x); acc0.y = fmaf(w2, hv2.y, acc0.y);
            acc0.z = fmaf(w2, hv2.z, acc0.z); acc0.w = fmaf(w2, hv2.w, acc0.w);
            acc1.x = fmaf(w3, hv3.x, acc1.x); acc1.y = fmaf(w3, hv3.y, acc1.y);
            acc1.z = fmaf(w3, hv3.z, acc1.z); acc1.w = fmaf(w3, hv3.w, acc1.w);
        }
        for (; j < cnt; j++){
            int s0 = __shfl(myidx, j, 64);
            float4 hv0 = ((const float4*)(h1 + (size_t)s0*HID))[lane];
            float4 a0 = ((const float4*)as1)[s0];
            float e0 = h==0?a0.x : h==1?a0.y : h==2?a0.z : a0.w;
            float w0 = __expf(lrelu(e0+adh));
            den += w0;
            acc0.x = fmaf(w0, hv0.x, acc0.x); acc0.y = fmaf(w0, hv0.y, acc0.y);
            acc0.z = fmaf(w0, hv0.z, acc0.z); acc0.w = fmaf(w0, hv0.w, acc0.w);
        }
    }
    float rs = 1.f/(den + 1e-16f);
    float4 b = ((const float4*)bias)[lane];
    float4 o;
    o.x = elu((acc0.x+acc1.x)*rs + b.x);
    o.y = elu((acc0.y+acc1.y)*rs + b.y);
    o.z = elu((acc0.z+acc1.z)*rs + b.z);
    o.w = elu((acc0.w+acc1.w)*rs + b.w);
    ((float4*)(x1 + (size_t)n*HID))[lane] = o;
}

// ---------- Layer 2 GEMM + fused attention coefficients ----------
__global__ void k_gemm2(const float* __restrict__ x1, const float* __restrict__ W2,
                        const float* __restrict__ att_s, const float* __restrict__ att_d,
                        float* __restrict__ h2, float* __restrict__ a2s,
                        float* __restrict__ a2d){
    __shared__ float xs[32][HID];         // 32 KB
    int row0 = blockIdx.x*32;
    int t = threadIdx.x;
    for (int i = t; i < 32*HID; i += 256)
        xs[i>>8][i&255] = x1[(size_t)(row0 + (i>>8))*HID + (i&255)];
    __syncthreads();
    int c  = t & 63;
    int r0 = (t >> 6)*8;
    float acc[8];
    #pragma unroll
    for (int r = 0; r < 8; r++) acc[r] = 0.f;
    for (int k = 0; k < HID; k++){
        float w = W2[k*OUTF + c];
        #pragma unroll
        for (int r = 0; r < 8; r++) acc[r] = fmaf(xs[r0+r][k], w, acc[r]);
    }
    float sv = att_s[c], dv = att_d[c];
    #pragma unroll
    for (int r = 0; r < 8; r++){
        h2[(size_t)(row0+r0+r)*OUTF + c] = acc[r];
        float ps = acc[r]*sv, pd = acc[r]*dv;
        #pragma unroll
        for (int off = 32; off >= 1; off >>= 1){
            ps += __shfl_xor(ps, off, 64);
            pd += __shfl_xor(pd, off, 64);
        }
        if (c == 0){
            a2s[row0+r0+r] = ps;
            a2d[row0+r0+r] = pd;
        }
    }
}

// ---------- layer-2 fused softmax+aggregate (single edge pass) ----------
__global__ void k_agg2(const float* __restrict__ h2, const int* __restrict__ rowptr,
                       const int* __restrict__ col, const float* __restrict__ a2s,
                       const float* __restrict__ a2d, const float* __restrict__ bias2,
                       float* __restrict__ out){
    int wv = threadIdx.x >> 6, lane = threadIdx.x & 63;
    int n = blockIdx.x*4 + wv;
    if (n >= NN) return;
    int beg = rowptr[n], end = rowptr[n+1];
    float adh = a2d[n];
    float den = 0.f;
    float acc0 = 0.f, acc1 = 0.f;
    for (int base = beg; base < end; base += 64){
        int cnt = min(64, end - base);
        int myidx = (lane < cnt) ? col[base + lane] : 0;
        int j = 0;
        for (; j + 4 <= cnt; j += 4){
            int s0 = __shfl(myidx, j,   64);
            int s1 = __shfl(myidx, j+1, 64);
            int s2 = __shfl(myidx, j+2, 64);
            int s3 = __shfl(myidx, j+3, 64);
            float hv0 = h2[(size_t)s0*OUTF + lane];
            float hv1 = h2[(size_t)s1*OUTF + lane];
            float hv2 = h2[(size_t)s2*OUTF + lane];
            float hv3 = h2[(size_t)s3*OUTF + lane];
            float w0 = __expf(lrelu(a2s[s0]+adh));
            float w1 = __expf(lrelu(a2s[s1]+adh));
            float w2 = __expf(lrelu(a2s[s2]+adh));
            float w3 = __expf(lrelu(a2s[s3]+adh));
            den += (w0+w1)+(w2+w3);
            acc0 = fmaf(w0, hv0, acc0);
            acc1 = fmaf(w1, hv1, acc1);
            acc0 = fmaf(w2, hv2, acc0);
            acc1 = fmaf(w3, hv3, acc1);
        }
        for (; j < cnt; j++){
            int s0 = __shfl(myidx, j, 64);
            float hv0 = h2[(size_t)s0*OUTF + lane];
            float w0 = __expf(lrelu(a2s[s0]+adh));
            den += w0;
            acc0 = fmaf(w0, hv0, acc0);
        }
    }
    out[(size_t)n*OUTF + lane] = (acc0+acc1)/(den + 1e-16f) + bias2[lane];
}

extern "C" void kernel_launch(void* const* d_in, const int* in_sizes, int n_in,
                              void* d_out, int out_size, void* d_ws, size_t ws_size,
                              hipStream_t stream){
    const float* x      = (const float*)d_in[0];
    const int*   ei     = (const int*)  d_in[1];
    const float* W1     = (const float*)d_in[2];
    const float* att_s1 = (const float*)d_in[3];
    const float* att_d1 = (const float*)d_in[4];
    const float* bias1  = (const float*)d_in[5];
    const float* W2     = (const float*)d_in[6];
    const float* att_s2 = (const float*)d_in[7];
    const float* att_d2 = (const float*)d_in[8];
    const float* bias2  = (const float*)d_in[9];
    int E = in_sizes[1] / 2;

    char* w = (char*)d_ws;
    size_t off = 0;
    auto alloc = [&](size_t b){ void* p = w + off; off += (b + 255) & ~(size_t)255; return p; };
    float* h1     = (float*)alloc((size_t)NN*HID*4);
    float* x1     = (float*)alloc((size_t)NN*HID*4);
    float* h2     = (float*)alloc((size_t)NN*OUTF*4);
    float* as1    = (float*)alloc((size_t)NN*NH*4);
    float* ad1    = (float*)alloc((size_t)NN*NH*4);
    float* a2s    = (float*)alloc((size_t)NN*4);
    float* a2d    = (float*)alloc((size_t)NN*4);
    int*   deg    = (int*)alloc((size_t)(NN+1)*4);
    int*   rowptr = (int*)alloc((size_t)(NN+1)*4);
    int*   cursor = (int*)alloc((size_t)NN*4);
    int*   col    = (int*)alloc((size_t)(E+NN)*4);

    k_deg_init<<<(NN+255)/256, 256, 0, stream>>>(deg);
    k_deg_hist<<<(E+255)/256, 256, 0, stream>>>(ei, deg, E);
    k_scan<<<1, 1024, 0, stream>>>(deg, rowptr);
    k_selfloop<<<(NN+255)/256, 256, 0, stream>>>(rowptr, col, cursor);
    k_scatter<<<(E+255)/256, 256, 0, stream>>>(ei, cursor, col, E);

    k_gemm1<<<NN/16, 256, 0, stream>>>(x, W1, att_s1, att_d1, h1, as1, ad1);
    k_agg1<<<(NN+3)/4, 256, 0, stream>>>(h1, rowptr, col, as1, ad1, bias1, x1);

    k_gemm2<<<NN/32, 256, 0, stream>>>(x1, W2, att_s2, att_d2, h2, a2s, a2d);
    k_agg2<<<(NN+3)/4, 256, 0, stream>>>(h2, rowptr, col, a2s, a2d, bias2, (float*)d_out);
}

// Round 4
// 324.788 us; speedup vs baseline: 1.3853x; 1.1636x over previous
//
#include <hip/hip_runtime.h>
#include <hip/hip_bf16.h>
#include <math.h>

#define NN   20000
#define INF  256
#define HID  256   // H*OUT = 4*64
#define NH   4
#define OUTF 64

__device__ __forceinline__ float lrelu(float x){ return x > 0.f ? x : 0.2f*x; }
__device__ __forceinline__ float elu(float x){ return x > 0.f ? x : __expf(x)-1.f; }

// ---------------- CSR build ----------------
__global__ void k_deg_init(int* deg){
    int i = blockIdx.x*blockDim.x + threadIdx.x;
    if (i < NN) deg[i] = 1;               // self-loop
}

__global__ void k_deg_hist(const int* __restrict__ ei, int* deg, int E){
    int e = blockIdx.x*blockDim.x + threadIdx.x;
    if (e < E) atomicAdd(&deg[ei[E + e]], 1);   // dst = ei[1][e]
}

__global__ void k_scan(const int* __restrict__ deg, int* __restrict__ rowptr){
    __shared__ int part[1024];
    int t = threadIdx.x;
    const int CH = 20;                    // 1024*20 >= 20000
    int base = t*CH;
    int s = 0;
    for (int i = 0; i < CH; i++){ int idx = base+i; if (idx < NN) s += deg[idx]; }
    part[t] = s;
    __syncthreads();
    for (int off = 1; off < 1024; off <<= 1){
        int v = (t >= off) ? part[t-off] : 0;
        __syncthreads();
        part[t] += v;
        __syncthreads();
    }
    int run = (t > 0) ? part[t-1] : 0;
    for (int i = 0; i < CH; i++){
        int idx = base+i;
        if (idx < NN){ rowptr[idx] = run; run += deg[idx]; }
    }
    if (t == 1023) rowptr[NN] = part[1023];
}

__global__ void k_selfloop(const int* __restrict__ rowptr, int* col, int* cursor){
    int n = blockIdx.x*blockDim.x + threadIdx.x;
    if (n < NN){ int p = rowptr[n]; col[p] = n; cursor[n] = p+1; }
}

__global__ void k_scatter(const int* __restrict__ ei, int* cursor, int* col, int E){
    int e = blockIdx.x*blockDim.x + threadIdx.x;
    if (e < E){
        int s = ei[e], d = ei[E + e];
        int pos = atomicAdd(&cursor[d], 1);
        col[pos] = s;
    }
}

// ---------- Layer 1 GEMM + fused attention coefficients ----------
// h1b (bf16 gather copy) = x @ W1; logits from fp32 accumulators.
__global__ void k_gemm1(const float* __restrict__ x, const float* __restrict__ W,
                        const float* __restrict__ att_s, const float* __restrict__ att_d,
                        __hip_bfloat16* __restrict__ h1b, float* __restrict__ as1,
                        float* __restrict__ ad1){
    __shared__ float xs[16][INF];
    int row0 = blockIdx.x*16;
    int t = threadIdx.x;
    int lane = t & 63, wv = t >> 6;
    for (int i = t; i < 16*INF; i += 256)
        xs[i>>8][i&255] = x[(size_t)(row0 + (i>>8))*INF + (i&255)];
    __syncthreads();
    float acc[16];
    #pragma unroll
    for (int r = 0; r < 16; r++) acc[r] = 0.f;
    for (int k = 0; k < INF; k++){
        float w = W[k*HID + t];
        #pragma unroll
        for (int r = 0; r < 16; r++) acc[r] = fmaf(xs[r][k], w, acc[r]);
    }
    float sv = att_s[t], dv = att_d[t];     // col t -> head t>>6, att flat [256]
    #pragma unroll
    for (int r = 0; r < 16; r++){
        h1b[(size_t)(row0+r)*HID + t] = __float2bfloat16(acc[r]);
        float ps = acc[r]*sv, pd = acc[r]*dv;
        #pragma unroll
        for (int off = 32; off >= 1; off >>= 1){
            ps += __shfl_xor(ps, off, 64);
            pd += __shfl_xor(pd, off, 64);
        }
        if (lane == 0){
            as1[(row0+r)*NH + wv] = ps;
            ad1[(row0+r)*NH + wv] = pd;
        }
    }
}

// ---------- layer-1 fused softmax+aggregate (single pass, bf16 gather) ----------
__global__ void k_agg1(const ushort* __restrict__ h1b, const int* __restrict__ rowptr,
                       const int* __restrict__ col, const float* __restrict__ as1,
                       const float* __restrict__ ad1, const float* __restrict__ bias,
                       float* __restrict__ x1){
    int wv = threadIdx.x >> 6, lane = threadIdx.x & 63;
    int n = blockIdx.x*4 + wv;
    if (n >= NN) return;
    int beg = rowptr[n], end = rowptr[n+1];
    float4 adst = ((const float4*)ad1)[n];
    int h = lane >> 4;
    float adh = h==0?adst.x : h==1?adst.y : h==2?adst.z : adst.w;
    float den = 0.f;
    float4 accs[4];
    #pragma unroll
    for (int u = 0; u < 4; u++) accs[u] = make_float4(0.f,0.f,0.f,0.f);

    for (int base = beg; base < end; base += 64){
        int cnt = min(64, end - base);
        int myidx = (lane < cnt) ? col[base + lane] : 0;
        int j = 0;
        for (; j + 8 <= cnt; j += 8){
            int ss[8];
            #pragma unroll
            for (int u = 0; u < 8; u++) ss[u] = __shfl(myidx, j+u, 64);
            uint2 hv[8];
            float aw[8];
            #pragma unroll
            for (int u = 0; u < 8; u++){
                hv[u] = *(const uint2*)(h1b + ((size_t)ss[u]<<8) + (lane<<2));
                aw[u] = as1[ss[u]*NH + h];           // 16B line broadcast per 16-lane group
            }
            #pragma unroll
            for (int u = 0; u < 8; u++){
                float w = __expf(lrelu(aw[u]+adh));
                den += w;
                float f0 = __uint_as_float(hv[u].x << 16);
                float f1 = __uint_as_float(hv[u].x & 0xFFFF0000u);
                float f2 = __uint_as_float(hv[u].y << 16);
                float f3 = __uint_as_float(hv[u].y & 0xFFFF0000u);
                accs[u&3].x = fmaf(w, f0, accs[u&3].x);
                accs[u&3].y = fmaf(w, f1, accs[u&3].y);
                accs[u&3].z = fmaf(w, f2, accs[u&3].z);
                accs[u&3].w = fmaf(w, f3, accs[u&3].w);
            }
        }
        for (; j < cnt; j++){
            int s0 = __shfl(myidx, j, 64);
            uint2 hv0 = *(const uint2*)(h1b + ((size_t)s0<<8) + (lane<<2));
            float aw0 = as1[s0*NH + h];
            float w = __expf(lrelu(aw0+adh));
            den += w;
            accs[0].x = fmaf(w, __uint_as_float(hv0.x << 16),        accs[0].x);
            accs[0].y = fmaf(w, __uint_as_float(hv0.x & 0xFFFF0000u), accs[0].y);
            accs[0].z = fmaf(w, __uint_as_float(hv0.y << 16),        accs[0].z);
            accs[0].w = fmaf(w, __uint_as_float(hv0.y & 0xFFFF0000u), accs[0].w);
        }
    }
    float rs = 1.f/(den + 1e-16f);
    float4 b = ((const float4*)bias)[lane];
    float4 o;
    o.x = elu((accs[0].x+accs[1].x+accs[2].x+accs[3].x)*rs + b.x);
    o.y = elu((accs[0].y+accs[1].y+accs[2].y+accs[3].y)*rs + b.y);
    o.z = elu((accs[0].z+accs[1].z+accs[2].z+accs[3].z)*rs + b.z);
    o.w = elu((accs[0].w+accs[1].w+accs[2].w+accs[3].w)*rs + b.w);
    ((float4*)(x1 + (size_t)n*HID))[lane] = o;
}

// ---------- Layer 2 GEMM + fused attention coefficients ----------
__global__ void k_gemm2(const float* __restrict__ x1, const float* __restrict__ W2,
                        const float* __restrict__ att_s, const float* __restrict__ att_d,
                        float* __restrict__ h2, float* __restrict__ a2s,
                        float* __restrict__ a2d){
    __shared__ float xs[32][HID];         // 32 KB
    int row0 = blockIdx.x*32;
    int t = threadIdx.x;
    for (int i = t; i < 32*HID; i += 256)
        xs[i>>8][i&255] = x1[(size_t)(row0 + (i>>8))*HID + (i&255)];
    __syncthreads();
    int c  = t & 63;
    int r0 = (t >> 6)*8;
    float acc[8];
    #pragma unroll
    for (int r = 0; r < 8; r++) acc[r] = 0.f;
    for (int k = 0; k < HID; k++){
        float w = W2[k*OUTF + c];
        #pragma unroll
        for (int r = 0; r < 8; r++) acc[r] = fmaf(xs[r0+r][k], w, acc[r]);
    }
    float sv = att_s[c], dv = att_d[c];
    #pragma unroll
    for (int r = 0; r < 8; r++){
        h2[(size_t)(row0+r0+r)*OUTF + c] = acc[r];
        float ps = acc[r]*sv, pd = acc[r]*dv;
        #pragma unroll
        for (int off = 32; off >= 1; off >>= 1){
            ps += __shfl_xor(ps, off, 64);
            pd += __shfl_xor(pd, off, 64);
        }
        if (c == 0){
            a2s[row0+r0+r] = ps;
            a2d[row0+r0+r] = pd;
        }
    }
}

// ---------- layer-2 fused softmax+aggregate (single pass, fp32) ----------
__global__ void k_agg2(const float* __restrict__ h2, const int* __restrict__ rowptr,
                       const int* __restrict__ col, const float* __restrict__ a2s,
                       const float* __restrict__ a2d, const float* __restrict__ bias2,
                       float* __restrict__ out){
    int wv = threadIdx.x >> 6, lane = threadIdx.x & 63;
    int n = blockIdx.x*4 + wv;
    if (n >= NN) return;
    int beg = rowptr[n], end = rowptr[n+1];
    float adh = a2d[n];
    float den = 0.f;
    float acc[4] = {0.f, 0.f, 0.f, 0.f};
    for (int base = beg; base < end; base += 64){
        int cnt = min(64, end - base);
        int myidx = (lane < cnt) ? col[base + lane] : 0;
        int j = 0;
        for (; j + 8 <= cnt; j += 8){
            int ss[8];
            #pragma unroll
            for (int u = 0; u < 8; u++) ss[u] = __shfl(myidx, j+u, 64);
            float hw[8], aw[8];
            #pragma unroll
            for (int u = 0; u < 8; u++){
                hw[u] = h2[(size_t)ss[u]*OUTF + lane];
                aw[u] = a2s[ss[u]];
            }
            #pragma unroll
            for (int u = 0; u < 8; u++){
                float w = __expf(lrelu(aw[u]+adh));
                den += w;
                acc[u&3] = fmaf(w, hw[u], acc[u&3]);
            }
        }
        for (; j < cnt; j++){
            int s0 = __shfl(myidx, j, 64);
            float hv0 = h2[(size_t)s0*OUTF + lane];
            float w0 = __expf(lrelu(a2s[s0]+adh));
            den += w0;
            acc[0] = fmaf(w0, hv0, acc[0]);
        }
    }
    out[(size_t)n*OUTF + lane] = (acc[0]+acc[1]+acc[2]+acc[3])/(den + 1e-16f) + bias2[lane];
}

extern "C" void kernel_launch(void* const* d_in, const int* in_sizes, int n_in,
                              void* d_out, int out_size, void* d_ws, size_t ws_size,
                              hipStream_t stream){
    const float* x      = (const float*)d_in[0];
    const int*   ei     = (const int*)  d_in[1];
    const float* W1     = (const float*)d_in[2];
    const float* att_s1 = (const float*)d_in[3];
    const float* att_d1 = (const float*)d_in[4];
    const float* bias1  = (const float*)d_in[5];
    const float* W2     = (const float*)d_in[6];
    const float* att_s2 = (const float*)d_in[7];
    const float* att_d2 = (const float*)d_in[8];
    const float* bias2  = (const float*)d_in[9];
    int E = in_sizes[1] / 2;

    char* w = (char*)d_ws;
    size_t off = 0;
    auto alloc = [&](size_t b){ void* p = w + off; off += (b + 255) & ~(size_t)255; return p; };
    __hip_bfloat16* h1b = (__hip_bfloat16*)alloc((size_t)NN*HID*2);
    float* x1     = (float*)alloc((size_t)NN*HID*4);
    float* h2     = (float*)alloc((size_t)NN*OUTF*4);
    float* as1    = (float*)alloc((size_t)NN*NH*4);
    float* ad1    = (float*)alloc((size_t)NN*NH*4);
    float* a2s    = (float*)alloc((size_t)NN*4);
    float* a2d    = (float*)alloc((size_t)NN*4);
    int*   deg    = (int*)alloc((size_t)(NN+1)*4);
    int*   rowptr = (int*)alloc((size_t)(NN+1)*4);
    int*   cursor = (int*)alloc((size_t)NN*4);
    int*   col    = (int*)alloc((size_t)(E+NN)*4);

    k_deg_init<<<(NN+255)/256, 256, 0, stream>>>(deg);
    k_deg_hist<<<(E+255)/256, 256, 0, stream>>>(ei, deg, E);
    k_scan<<<1, 1024, 0, stream>>>(deg, rowptr);
    k_selfloop<<<(NN+255)/256, 256, 0, stream>>>(rowptr, col, cursor);
    k_scatter<<<(E+255)/256, 256, 0, stream>>>(ei, cursor, col, E);

    k_gemm1<<<NN/16, 256, 0, stream>>>(x, W1, att_s1, att_d1, h1b, as1, ad1);
    k_agg1<<<(NN+3)/4, 256, 0, stream>>>((const ushort*)h1b, rowptr, col, as1, ad1, bias1, x1);

    k_gemm2<<<NN/32, 256, 0, stream>>>(x1, W2, att_s2, att_d2, h2, a2s, a2d);
    k_agg2<<<(NN+3)/4, 256, 0, stream>>>(h2, rowptr, col, a2s, a2d, bias2, (float*)d_out);
}